// Round 9
// baseline (26384.604 us; speedup 1.0000x reference)
//
#include <hip/hip_runtime.h>
#include <stdint.h>

#define DEVINL __device__ __forceinline__

constexpr int B_  = 32;
constexpr int S_  = 512;
constexpr int I_  = 768;
constexpr int H_  = 512;
constexpr int C_  = 10;
constexpr int R_  = 64;     // 2 dirs * B_
constexpr int G4H = 2048;   // 4*H_
constexpr int I2_ = 1536;   // 2*I_
constexpr int NBLK = 256;   // persistent grid (1 block/CU co-resident)
constexpr int NTHR = 512;

using bf16x8 = __attribute__((ext_vector_type(8))) short;
using f32x4  = __attribute__((ext_vector_type(4))) float;
typedef unsigned short u16;
typedef unsigned int   u32;

// ---------------- workspace layout (bytes) ----------------
constexpr size_t OFF_TE   = 0;
constexpr size_t OFF_EMB  = OFF_TE   + (size_t)B_*S_*H_*2;
constexpr size_t OFF_WDEC = OFF_EMB  + (size_t)B_*S_*I_*2;
constexpr size_t OFF_WHH  = OFF_WDEC + (size_t)H_*H_*2;
constexpr size_t OFF_WIL  = OFF_WHH  + (size_t)2*G4H*H_*2;
constexpr size_t OFF_WIR  = OFF_WIL  + (size_t)2*G4H*I_*2;
constexpr size_t OFF_WENC = OFF_WIR  + (size_t)2*G4H*I_*2;
constexpr size_t OFF_H    = OFF_WENC + (size_t)H_*I_*2;
constexpr size_t OFF_C    = OFF_H    + (size_t)R_*H_*2;
constexpr size_t OFF_TD   = OFF_C    + (size_t)R_*H_*4;
constexpr size_t OFF_HWH  = OFF_TD   + (size_t)R_*H_*4;
constexpr size_t OFF_XW   = OFF_HWH  + (size_t)R_*G4H*4;
constexpr size_t OFF_CTX  = OFF_XW   + (size_t)R_*G4H*4;
constexpr size_t OFF_SUME = OFF_CTX  + (size_t)R_*I_*4;
constexpr size_t OFF_M    = OFF_SUME + 256;
// barrier: bar[32]=generation; bar[64+b*32]=block b arrival flag (own line)
constexpr size_t OFF_BAR  = OFF_M    + 256;
constexpr int    BAR_W    = 64 + NBLK*32;
// producer/consumer flags (own 128B line each, monotonic value = t+1)
constexpr size_t OFF_DECF = OFF_BAR  + BAR_W*4;     // [32] dec-tile done
constexpr size_t OFF_ZF   = OFF_DECF + 32*32*4;     // [32] ctx/sumE zeroed
constexpr size_t OFF_AF   = OFF_ZF   + 32*32*4;     // [256] A-block (Whh+WIR) done
constexpr size_t WS_NEED  = OFF_AF + 256*32*4;

// ---------------- helpers ----------------
DEVINL float asf(u32 u){ union{u32 i; float f;} x; x.i=u; return x.f; }
DEVINL u32   asu(float f){ union{u32 i; float f;} x; x.f=f; return x.i; }
DEVINL float bf2f(u16 h){ return asf((u32)h << 16); }
DEVINL u16   f2bf(float f){ u32 u = asu(f); return (u16)((u + 0x7fffu + ((u>>16)&1u)) >> 16); }
DEVINL float frcp(float x){
#if __has_builtin(__builtin_amdgcn_rcpf)
  return __builtin_amdgcn_rcpf(x);
#else
  return 1.0f/x;
#endif
}
DEVINL float sigm(float x){ return frcp(1.0f + __expf(-x)); }

DEVINL float ldc_f(const float* p){ return __hip_atomic_load(p, __ATOMIC_RELAXED, __HIP_MEMORY_SCOPE_AGENT); }
DEVINL void  stc_f(float* p, float v){ __hip_atomic_store(p, v, __ATOMIC_RELAXED, __HIP_MEMORY_SCOPE_AGENT); }
DEVINL u32   ldc_u(const u32* p){ return __hip_atomic_load(p, __ATOMIC_RELAXED, __HIP_MEMORY_SCOPE_AGENT); }
DEVINL void  stc_u(u32* p, u32 v){ __hip_atomic_store(p, v, __ATOMIC_RELAXED, __HIP_MEMORY_SCOPE_AGENT); }
DEVINL void  addc_f(float* p, float v){ __hip_atomic_fetch_add(p, v, __ATOMIC_RELAXED, __HIP_MEMORY_SCOPE_AGENT); }
// drain outstanding vector-memory ops (stores ack'd at coherence point)
DEVINL void vm_drain(){ asm volatile("s_waitcnt vmcnt(0)" ::: "memory"); }

// grid barrier v3 (validated R8): contention-free arrival flags + block0 publish
DEVINL void gridbar(u32* bar, u32 n){
  __syncthreads();
  if (threadIdx.x == 0)
    stc_u(&bar[64 + blockIdx.x*32], n);
  if (blockIdx.x == 0){
    if (threadIdx.x < NBLK){
      while (ldc_u(&bar[64 + threadIdx.x*32]) < n)
        __builtin_amdgcn_s_sleep(1);
    }
    __syncthreads();
    if (threadIdx.x == 0) stc_u(&bar[32], n);
  } else {
    if (threadIdx.x == 0){
      while (ldc_u(&bar[32]) < n)
        __builtin_amdgcn_s_sleep(1);
    }
  }
  __syncthreads();
}

// M=16 GEMM over K=512, A = h rows (coherent loads), B = LDS panel [16][520]
DEVINL f32x4 gemm_h16(const u32* h32, size_t base, const u16 (*W)[520], int lr, int lkb){
  f32x4 acc = {0.f,0.f,0.f,0.f};
  #pragma unroll
  for (int half = 0; half < 2; ++half){
    u32 hreg[32];
    #pragma unroll
    for (int i2 = 0; i2 < 32; ++i2)
      hreg[i2] = ldc_u(h32 + base + half*128 + (i2>>2)*16 + (i2&3));
    #pragma unroll
    for (int ki = 0; ki < 8; ++ki){
      union { bf16x8 v; u32 w[4]; } ua;
      ua.w[0]=hreg[ki*4+0]; ua.w[1]=hreg[ki*4+1];
      ua.w[2]=hreg[ki*4+2]; ua.w[3]=hreg[ki*4+3];
      bf16x8 b = *(const bf16x8*)(&W[lr][(half*8+ki)*32 + lkb]);
      acc = __builtin_amdgcn_mfma_f32_16x16x32_bf16(ua.v, b, acc, 0, 0, 0);
    }
  }
  return acc;
}

// ---------------- shared-memory union (phase-transient) ----------------
struct SMemB { float ldsE[2][2][32]; float cpart[4][96][16]; };
struct SMemC { u16 Abuf[16][776]; float Gpre[32][16]; float Gs[32][16];
               float Hb[16][8]; float inv[16]; float sum[16]; };
union alignas(16) SMem { SMemB b; SMemC c; };

// ---------------- one-time setup ----------------
__global__ void k_setup(char* ws, const float* Wenc, const float* Wdec,
                        const float* Whh_f, const float* Whh_b,
                        const float* Wih_f, const float* Wih_b,
                        float* out){
  int tid = blockIdx.x*blockDim.x + threadIdx.x;
  int nth = gridDim.x*blockDim.x;
  for (int i = tid; i < B_*S_*C_; i += nth) out[i] = 0.f;
  u16* hB = (u16*)(ws+OFF_H);
  for (int i = tid; i < R_*H_; i += nth) hB[i] = 0;
  float* cS = (float*)(ws+OFF_C);
  for (int i = tid; i < R_*H_; i += nth) cS[i] = 0.f;
  float* mb = (float*)(ws+OFF_M);
  for (int i = tid; i < R_; i += nth) mb[i] = 0.f;
  float* ctx = (float*)(ws+OFF_CTX);
  for (int i = tid; i < R_*I_; i += nth) ctx[i] = 0.f;
  float* se = (float*)(ws+OFF_SUME);
  for (int i = tid; i < R_; i += nth) se[i] = 0.f;
  u32* bar = (u32*)(ws+OFF_BAR);
  for (int i = tid; i < BAR_W; i += nth) bar[i] = 0u;
  u32* fl = (u32*)(ws+OFF_DECF);
  for (int i = tid; i < (32+32+256)*32; i += nth) fl[i] = 0u;
  u16* wd = (u16*)(ws+OFF_WDEC);
  for (int i = tid; i < H_*H_; i += nth) wd[i] = f2bf(Wdec[i]);
  u16* we = (u16*)(ws+OFF_WENC);
  for (int i = tid; i < H_*I_; i += nth) we[i] = f2bf(Wenc[i]);
  u16* wh = (u16*)(ws+OFF_WHH);
  for (int i = tid; i < G4H*H_; i += nth){
    wh[i] = f2bf(Whh_f[i]);
    wh[G4H*H_ + i] = f2bf(Whh_b[i]);
  }
  u16* wl = (u16*)(ws+OFF_WIL);
  u16* wr = (u16*)(ws+OFF_WIR);
  for (int i = tid; i < G4H*I_; i += nth){
    int n = i / I_, k = i - n*I_;
    wl[i]            = f2bf(Wih_f[n*I2_ + k]);
    wr[i]            = f2bf(Wih_f[n*I2_ + I_ + k]);
    wl[G4H*I_ + i]   = f2bf(Wih_b[n*I2_ + k]);
    wr[G4H*I_ + i]   = f2bf(Wih_b[n*I2_ + I_ + k]);
  }
}

// ---------------- one-time: embeds -> bf16 ----------------
__global__ void k_embconv(char* ws, const float* emb){
  u16* e = (u16*)(ws+OFF_EMB);
  int tid = blockIdx.x*blockDim.x + threadIdx.x;
  int nth = gridDim.x*blockDim.x;
  int n4 = (B_*S_*I_)/4;
  const float4* src = (const float4*)emb;
  ushort4* dst = (ushort4*)e;
  for (int i = tid; i < n4; i += nth){
    float4 x = src[i];
    ushort4 o;
    o.x = f2bf(x.x); o.y = f2bf(x.y); o.z = f2bf(x.z); o.w = f2bf(x.w);
    dst[i] = o;
  }
}

// ---------------- one-time: Te = tanh(embB @ WencB^T + benc) ----------------
__global__ __launch_bounds__(256) void k_enc(char* ws, const float* benc){
  const u16* A = (const u16*)(ws+OFF_EMB);
  const u16* W = (const u16*)(ws+OFF_WENC);
  u16* Te = (u16*)(ws+OFF_TE);
  int wg = blockIdx.x;
  int mt = wg >> 3, ng = wg & 7;
  int wave = threadIdx.x >> 6, lane = threadIdx.x & 63;
  int m0 = mt*16, n0 = ng*64 + wave*16;
  int lr = lane & 15, lkb = (lane>>4)*8;
  const u16* ap = A + (size_t)(m0+lr)*I_ + lkb;
  const u16* bp = W + (size_t)(n0+lr)*I_ + lkb;
  f32x4 acc = {0.f,0.f,0.f,0.f};
  for (int k = 0; k < I_; k += 32){
    bf16x8 a = *(const bf16x8*)(ap + k);
    bf16x8 b = *(const bf16x8*)(bp + k);
    acc = __builtin_amdgcn_mfma_f32_16x16x32_bf16(a, b, acc, 0, 0, 0);
  }
  int row4 = (lane>>4)*4;
  #pragma unroll
  for (int q = 0; q < 4; q++){
    int rr = m0 + row4 + q, cc = n0 + lr;
    Te[(size_t)rr*H_ + cc] = f2bf(tanhf(acc[q] + benc[cc]));
  }
}

// ---------------- persistent stepper: 2 full barriers + flag waits per step ----------------
__global__ __launch_bounds__(NTHR) void k_persist(char* ws,
        const float* bdec, const float* v,
        const float* bih_f, const float* bhh_f,
        const float* bih_b, const float* bhh_b,
        const float* Wout, const float* bout, float* out){
  __shared__ SMem sh;
  __shared__ alignas(16) u16 wWhh[16][520];
  __shared__ alignas(16) u16 wWIR[16][776];
  __shared__ alignas(16) u16 wDec[16][520];
  __shared__ alignas(16) u16 wWIL[32][776];
  __shared__ float wOutL[10][8];
  __shared__ float bsumL[32];
  __shared__ u32 cntDec, cntZ, cntA;
  u32* bar  = (u32*)(ws+OFF_BAR);
  u32* decf = (u32*)(ws+OFF_DECF);
  u32* zf   = (u32*)(ws+OFF_ZF);
  u32* af   = (u32*)(ws+OFF_AF);
  u32 gen = 0;
  const int tid = threadIdx.x, lane = tid & 63, wave = tid >> 6;
  const int lr = lane & 15, lkb = (lane>>4)*8, row4 = (lane>>4)*4;
  const int blk = blockIdx.x;
  const int dirA = blk & 1, n0A = blk >> 1;
  const int ab   = blk & 31, pair = blk >> 5;
  const int s0A  = pair*32, s0B = S_ - pair*32 - 32;
  const int h0   = lane*8;
  const int cg   = (tid < 384) ? (tid % 96) : 0;
  const int rq   = (tid < 384) ? (tid / 96) : 0;
  const int dirC = blk >> 7, ncC = (blk >> 1) & 63, qbC = blk & 1;

  if (tid == 0){ cntDec = 0u; cntZ = 0u; cntA = 0u; }

  // ---- prologue: pin weights into LDS ----
  { const u16* src = (const u16*)(ws+OFF_WHH) + (size_t)dirA*G4H*H_ + (size_t)n0A*16*H_;
    for (int idx = tid; idx < 16*64; idx += NTHR){ int r = idx>>6, c8 = idx&63;
      *(uint4*)&wWhh[r][c8*8] = *(const uint4*)(src + (size_t)r*H_ + c8*8); } }
  { const u16* src = (const u16*)(ws+OFF_WIR) + (size_t)dirA*G4H*I_ + (size_t)n0A*16*I_;
    for (int idx = tid; idx < 16*96; idx += NTHR){ int r = idx/96, c8 = idx - r*96;
      *(uint4*)&wWIR[r][c8*8] = *(const uint4*)(src + (size_t)r*I_ + c8*8); } }
  if (blk < 32){
    const u16* src = (const u16*)(ws+OFF_WDEC) + (size_t)blk*16*H_;
    for (int idx = tid; idx < 16*64; idx += NTHR){ int r = idx>>6, c8 = idx&63;
      *(uint4*)&wDec[r][c8*8] = *(const uint4*)(src + (size_t)r*H_ + c8*8); } }
  { const u16* src = (const u16*)(ws+OFF_WIL) + (size_t)dirC*G4H*I_;
    for (int idx = tid; idx < 32*96; idx += NTHR){ int pr = idx/96, c8 = idx - pr*96;
      int g = pr>>3, j = pr&7;
      *(uint4*)&wWIL[pr][c8*8] = *(const uint4*)(src + (size_t)(g*512 + ncC*8 + j)*I_ + c8*8); } }
  { const float* bihp = dirC ? bih_b : bih_f;
    const float* bhhp = dirC ? bhh_b : bhh_f;
    if (tid < 32){ int g = tid>>3, c = tid&7; int n = g*512 + ncC*8 + c;
      bsumL[tid] = bihp[n] + bhhp[n]; }
    if (tid >= 64 && tid < 144){ int q = tid-64; int cc = q>>3, c = q&7;
      wOutL[cc][c] = Wout[(size_t)cc*1024 + dirC*512 + ncC*8 + c]; } }
  bf16x8 teR[8];
  { const u16* Te = (const u16*)(ws+OFF_TE);
    #pragma unroll
    for (int k = 0; k < 8; ++k){
      int r = wave + 8*k; int ci = r >> 5, u = r & 31;
      int s = (ci ? s0B : s0A) + u;
      teR[k] = *(const bf16x8*)(Te + ((size_t)(ab*S_ + s))*H_ + h0); } }
  bf16x8 embR[16];
  if (tid < 384){
    const u16* E = (const u16*)(ws+OFF_EMB);
    #pragma unroll
    for (int j = 0; j < 16; ++j){
      int r = rq*16 + j;
      int s = (r < 32) ? (s0A + r) : (s0B + (r - 32));
      embR[j] = *(const bf16x8*)(E + ((size_t)(ab*S_ + s))*I_ + cg*8); } }
  __syncthreads();

  for (int t = 0; t < S_; ++t){
    const u32 tg = (u32)t + 1u;
    // ===== phase A: Whh/WIR all blocks (waves 0-3); dec blocks 0-31 (waves 4-7);
    //       ctx/sumE zero blocks 32-63 (waves 4-7). Flags raised per producer. =====
    {
      const u32* h32 = (const u32*)(ws+OFF_H);
      if (wave < 2){                 // Whh tile
        int m0 = dirA*32 + wave*16;
        size_t base = (((size_t)(m0+lr))*H_ + lkb) >> 1;
        f32x4 acc = gemm_h16(h32, base, wWhh, lr, lkb);
        float* o = (float*)(ws+OFF_HWH);
        #pragma unroll
        for (int q = 0; q < 4; q++)
          stc_f(&o[(size_t)(m0 + row4 + q)*G4H + n0A*16 + lr], acc[q]);
        vm_drain();
        if (lane == 0){
          u32 old = atomicAdd(&cntA, 1u);
          if (old == 4u*tg - 1u) stc_u(&af[blk*32], tg);
        }
      } else if (wave < 4){          // WIR tile
        int bbase = (wave-2)*16;
        int trow = dirA ? (S_-1-t) : t;
        const u16* E = (const u16*)(ws+OFF_EMB);
        const u16* ap = E + ((size_t)(bbase+lr)*S_ + trow)*I_ + lkb;
        f32x4 acc = {0.f,0.f,0.f,0.f};
        for (int k = 0; k < I_; k += 32){
          bf16x8 a = *(const bf16x8*)(ap + k);
          bf16x8 b = *(const bf16x8*)(&wWIR[lr][k + lkb]);
          acc = __builtin_amdgcn_mfma_f32_16x16x32_bf16(a, b, acc, 0, 0, 0);
        }
        float* o = (float*)(ws+OFF_XW);
        #pragma unroll
        for (int q = 0; q < 4; q++)
          stc_f(&o[(size_t)(dirA*32 + bbase + row4 + q)*G4H + n0A*16 + lr], acc[q]);
        vm_drain();
        if (lane == 0){
          u32 old = atomicAdd(&cntA, 1u);
          if (old == 4u*tg - 1u) stc_u(&af[blk*32], tg);
        }
      } else if (blk < 32){          // dec tile
        int m0 = (wave-4)*16;
        size_t base = (((size_t)(m0+lr))*H_ + lkb) >> 1;
        f32x4 acc = gemm_h16(h32, base, wDec, lr, lkb);
        float* Td = (float*)(ws+OFF_TD);
        #pragma unroll
        for (int q = 0; q < 4; q++){
          int rr = m0 + row4 + q, cc = blk*16 + lr;
          stc_f(&Td[rr*H_ + cc], tanhf(acc[q] + bdec[cc]));
        }
        vm_drain();
        if (lane == 0){
          u32 old = atomicAdd(&cntDec, 1u);
          if (old == 4u*tg - 1u) stc_u(&decf[blk*32], tg);
        }
      } else if (blk < 64){          // zero ctx rows (blk-32)*2..+1 and sumE
        int z = blk - 32;
        float* ctx = (float*)(ws+OFF_CTX) + (size_t)z*2*I_;
        int q = (wave-4)*64 + lane;        // 0..255
        #pragma unroll
        for (int i2 = 0; i2 < 6; ++i2) stc_f(&ctx[q*6 + i2], 0.f);
        if (q < 2) stc_f((float*)(ws+OFF_SUME) + z*2 + q, 0.f);
        vm_drain();
        if (lane == 0){
          u32 old = atomicAdd(&cntZ, 1u);
          if (old == 4u*tg - 1u) stc_u(&zf[z*32], tg);
        }
      }
    }
    // ===== flag-wait: dec tiles ready (replaces full barrier #1) =====
    if (lane < 32){
      while (ldc_u(&decf[lane*32]) < tg) __builtin_amdgcn_s_sleep(1);
    }
    // ===== phase B: scores, exp, ctx gather =====
    {
      const float* Td = (const float*)(ws+OFF_TD);
      const float* mbp = (const float*)(ws+OFF_M);
      float tdf[8], tdb[8], va[8];
      #pragma unroll
      for (int j = 0; j < 8; j++){
        tdf[j] = ldc_f(&Td[ab*H_ + h0 + j]);
        tdb[j] = ldc_f(&Td[(32+ab)*H_ + h0 + j]);
        va[j]  = v[h0 + j];
      }
      float mF = ldc_f(&mbp[ab]), mB = ldc_f(&mbp[32+ab]);
      #pragma unroll
      for (int k = 0; k < 8; ++k){
        int r = wave + 8*k;
        int ci = r >> 5, u = r & 31;
        bf16x8 tv = teR[k];
        float af2 = 0.f, ab2 = 0.f;
        #pragma unroll
        for (int j = 0; j < 8; ++j){
          float te = bf2f((u16)tv[j]);
          float df = fmaf(te, tdf[j], 1.0f);
          float db = fmaf(te, tdb[j], 1.0f);
          af2 = fmaf((te+tdf[j])*frcp(df), va[j], af2);
          ab2 = fmaf((te+tdb[j])*frcp(db), va[j], ab2);
        }
        #pragma unroll
        for (int off = 1; off < 64; off <<= 1){
          af2 += __shfl_xor(af2, off);
          ab2 += __shfl_xor(ab2, off);
        }
        float ef = __expf(fminf(fmaxf(af2 - mF, -80.f), 80.f));
        float eb = __expf(fminf(fmaxf(ab2 - mB, -80.f), 80.f));
        if (lane == 0){ sh.b.ldsE[0][ci][u] = ef; sh.b.ldsE[1][ci][u] = eb; }
      }
      __syncthreads();
      if (tid < 384){
        const int ci = rq >> 1;
        float cf[8] = {0,0,0,0,0,0,0,0}, cb[8] = {0,0,0,0,0,0,0,0};
        #pragma unroll
        for (int j = 0; j < 16; ++j){
          int u = ((rq & 1) << 4) + j;
          float wf = sh.b.ldsE[0][ci][u];
          float wb = sh.b.ldsE[1][1-ci][31-u];
          bf16x8 e = embR[j];
          #pragma unroll
          for (int x = 0; x < 8; ++x){
            float ev = bf2f((u16)e[x]);
            cf[x] = fmaf(wf, ev, cf[x]);
            cb[x] = fmaf(wb, ev, cb[x]);
          }
        }
        #pragma unroll
        for (int x = 0; x < 8; ++x){
          sh.b.cpart[rq][cg][x]   = cf[x];
          sh.b.cpart[rq][cg][8+x] = cb[x];
        }
      }
      // wait: ctx/sumE zeroed (overlapped with the compute above)
      if (lane < 32){
        while (ldc_u(&zf[lane*32]) < tg) __builtin_amdgcn_s_sleep(1);
      }
      __syncthreads();
      if (tid < 2){
        float s = 0.f;
        for (int ci = 0; ci < 2; ci++)
          for (int u = 0; u < 32; u++) s += sh.b.ldsE[tid][ci][u];
        addc_f((float*)(ws+OFF_SUME) + tid*32 + ab, s);
      }
      {
        float* ctxg = (float*)(ws+OFF_CTX);
        for (int o = tid; o < 1536; o += NTHR){
          int d = (o >= 768) ? 1 : 0;
          int col = o - d*768;
          int cgx = col >> 3, c = col & 7;
          float s = sh.b.cpart[0][cgx][d*8+c] + sh.b.cpart[1][cgx][d*8+c]
                  + sh.b.cpart[2][cgx][d*8+c] + sh.b.cpart[3][cgx][d*8+c];
          addc_f(&ctxg[(size_t)(d*32+ab)*I_ + col], s);
        }
      }
    }
    // ===== Gpre prefetch (hidden behind bar wait): xW+hW for C, A-flag guarded =====
    float pf0 = 0.f, pf1 = 0.f;
    if (tid >= 128){
      const float* xW = (const float*)(ws+OFF_XW);
      const float* hW = (const float*)(ws+OFF_HWH);
      {
        int ii = tid - 128;            // 0..383 (<512 always)
        int pr = ii >> 4, j = ii & 15;
        int g = pr >> 3, c = pr & 7;
        int n = g*512 + ncC*8 + c;
        int ablk = (g*32 + (ncC>>1))*2 + dirC;
        while (ldc_u(&af[ablk*32]) < tg) __builtin_amdgcn_s_sleep(1);
        size_t rr = (size_t)(dirC*32 + qbC*16 + j);
        pf0 = ldc_f(&xW[rr*G4H + n]) + ldc_f(&hW[rr*G4H + n]);
      }
      int ii1 = (tid - 128) + 384;
      if (ii1 < 512){
        int pr = ii1 >> 4, j = ii1 & 15;
        int g = pr >> 3, c = pr & 7;
        int n = g*512 + ncC*8 + c;
        int ablk = (g*32 + (ncC>>1))*2 + dirC;
        while (ldc_u(&af[ablk*32]) < tg) __builtin_amdgcn_s_sleep(1);
        size_t rr = (size_t)(dirC*32 + qbC*16 + j);
        pf1 = ldc_f(&xW[rr*G4H + n]) + ldc_f(&hW[rr*G4H + n]);
      }
    }
    gridbar(bar, ++gen);
    // ===== phase C: ctx@WihL^T, LSTM cell, out projection =====
    {
      const float* se = (const float*)(ws+OFF_SUME) + dirC*32 + qbC*16;
      if (tid < 16){
        float s_ = ldc_f(&se[tid]);
        sh.c.sum[tid] = s_;
        sh.c.inv[tid] = 1.0f / fmaxf(s_, 1e-30f);
      }
      __syncthreads();
      {
        const float* ctx = (const float*)(ws+OFF_CTX) + (size_t)(dirC*32 + qbC*16)*I_;
        float creg[24];
        int j = tid >> 5, k0 = (tid & 31) * 24;
        #pragma unroll
        for (int i2 = 0; i2 < 24; ++i2)
          creg[i2] = ldc_f(ctx + (size_t)j*I_ + k0 + i2);
        float inv = sh.c.inv[j];
        #pragma unroll
        for (int i2 = 0; i2 < 24; ++i2)
          sh.c.Abuf[j][k0 + i2] = f2bf(creg[i2] * inv);
      }
      __syncthreads();
      f32x4 acc = {0.f,0.f,0.f,0.f};
      if (wave < 2){
        for (int k = 0; k < I_; k += 32){
          bf16x8 av = *(const bf16x8*)(&sh.c.Abuf[lr][k + lkb]);
          bf16x8 bv = *(const bf16x8*)(&wWIL[wave*16 + lr][k + lkb]);
          acc = __builtin_amdgcn_mfma_f32_16x16x32_bf16(av, bv, acc, 0, 0, 0);
        }
      } else {                       // Gpre from prefetched registers
        {
          int ii = tid - 128;
          int pr = ii >> 4, j = ii & 15;
          sh.c.Gpre[pr][j] = pf0 + bsumL[pr];
        }
        int ii1 = (tid - 128) + 384;
        if (ii1 < 512){
          int pr = ii1 >> 4, j = ii1 & 15;
          sh.c.Gpre[pr][j] = pf1 + bsumL[pr];
        }
      }
      __syncthreads();
      if (wave < 2){
        int pr = wave*16 + lr;
        #pragma unroll
        for (int q = 0; q < 4; q++){
          int j = row4 + q;
          sh.c.Gs[pr][j] = acc[q] + sh.c.Gpre[pr][j];
        }
      }
      __syncthreads();
      float* cS = (float*)(ws+OFF_C);
      if (tid < 128){
        int j = tid >> 3, c = tid & 7;
        int hg = ncC*8 + c;
        size_t rr = (size_t)(dirC*32 + qbC*16 + j);
        float ig = sigm(sh.c.Gs[c][j]);
        float fg = sigm(sh.c.Gs[8+c][j]);
        float gg = tanhf(sh.c.Gs[16+c][j]);
        float og = sigm(sh.c.Gs[24+c][j]);
        float cn = fmaf(fg, cS[rr*H_ + hg], ig*gg);
        float hn = og * tanhf(cn);
        cS[rr*H_ + hg] = cn;
        sh.c.Hb[j][c] = hn;
      }
      __syncthreads();
      if (tid < 64){
        int j = tid >> 2, cp = tid & 3;
        size_t rr = (size_t)(dirC*32 + qbC*16 + j);
        u32 pk = (u32)f2bf(sh.c.Hb[j][cp*2]) | ((u32)f2bf(sh.c.Hb[j][cp*2+1]) << 16);
        stc_u((u32*)(ws+OFF_H) + ((rr*H_ + ncC*8) >> 1) + cp, pk);
      }
      if (tid < 160){
        int j = tid/10, cc = tid - j*10;
        float s = 0.f;
        #pragma unroll
        for (int c = 0; c < 8; c++) s = fmaf(sh.c.Hb[j][c], wOutL[cc][c], s);
        if (dirC == 0 && ncC == 0) s += bout[cc];
        int bb = qbC*16 + j;
        int st = dirC ? (S_-1-t) : t;
        atomicAdd(&out[((size_t)bb*S_ + st)*C_ + cc], s);
      }
      if (ncC == 0 && tid < 16){
        float* mp = (float*)(ws+OFF_M) + dirC*32 + qbC*16 + tid;
        stc_f(mp, ldc_f(mp) + logf(fmaxf(sh.c.sum[tid], 1e-30f)));
      }
    }
    gridbar(bar, ++gen);
  }
}

// ---------------- host launcher ----------------
extern "C" void kernel_launch(void* const* d_in, const int* in_sizes, int n_in,
                              void* d_out, int out_size, void* d_ws, size_t ws_size,
                              hipStream_t stream){
  const float* emb   = (const float*)d_in[0];
  const float* Wenc  = (const float*)d_in[1];
  const float* benc  = (const float*)d_in[2];
  const float* Wdec  = (const float*)d_in[3];
  const float* bdec  = (const float*)d_in[4];
  const float* v     = (const float*)d_in[5];
  const float* Wih_f = (const float*)d_in[6];
  const float* Whh_f = (const float*)d_in[7];
  const float* bih_f = (const float*)d_in[8];
  const float* bhh_f = (const float*)d_in[9];
  const float* Wih_b = (const float*)d_in[10];
  const float* Whh_b = (const float*)d_in[11];
  const float* bih_b = (const float*)d_in[12];
  const float* bhh_b = (const float*)d_in[13];
  const float* Wout  = (const float*)d_in[14];
  const float* bout  = (const float*)d_in[15];
  float* out = (float*)d_out;
  char* ws = (char*)d_ws;
  if (ws_size < WS_NEED) return;   // fail loudly via validation

  k_setup<<<dim3(512), dim3(256), 0, stream>>>(ws, Wenc, Wdec, Whh_f, Whh_b, Wih_f, Wih_b, out);
  k_embconv<<<dim3(2048), dim3(256), 0, stream>>>(ws, emb);
  k_enc<<<dim3(8192), dim3(256), 0, stream>>>(ws, benc);
  k_persist<<<dim3(NBLK), dim3(NTHR), 0, stream>>>(ws, bdec, v,
      bih_f, bhh_f, bih_b, bhh_b, Wout, bout, out);
}